// Round 2
// baseline (718.113 us; speedup 1.0000x reference)
//
#include <hip/hip_runtime.h>

#define HID 2048
#define NE 64
#define NTOK 32768        // GROUPS * TOKENS = 4 * 8192
#define CAP 160
#define GAP_THR 1e-3f

// ---------------------------------------------------------------------------
// K1: logits GEMM + softmax-max + top-2.  Block = 512 thr = 8 waves.
// Wave w: tokens [half*64 .. +64) (lane = token), experts [(w&3)*16 .. +16),
// full H sweep. acc[16] per thread — compile-time indexed, cannot spill.
// W addresses are wave-uniform -> scalar loads; no cross-wave reduction.
// ---------------------------------------------------------------------------
__global__ __launch_bounds__(512, 4) void k_logits(
    const float* __restrict__ A, const float* __restrict__ W,
    const float* __restrict__ bias,
    float* __restrict__ logits, float* __restrict__ probsmax,
    int* __restrict__ choice, int* __restrict__ idx2o, float* __restrict__ gapo)
{
    __shared__ float lacc[128][65];   // +1 pad: conflict-free row access
    const int tid  = threadIdx.x;
    const int wv   = tid >> 6;        // 0..7
    const int lane = tid & 63;
    const int half = wv >> 2;         // 0/1: which 64-token half
    const int e0   = (wv & 3) * 16;   // expert quadrant
    const int trow = half * 64 + lane;
    const int tok  = blockIdx.x * 128 + trow;

    const float* a  = A + (size_t)tok * HID;
    const float* wb = W + (size_t)e0 * HID;

    float acc[16];
#pragma unroll
    for (int e = 0; e < 16; ++e) acc[e] = 0.0f;

#pragma unroll 1
    for (int h0 = 0; h0 < HID; h0 += 8) {
        const float4 t0 = *(const float4*)(a + h0);
        const float4 t1 = *(const float4*)(a + h0 + 4);
        const float av[8] = {t0.x, t0.y, t0.z, t0.w, t1.x, t1.y, t1.z, t1.w};
#pragma unroll
        for (int e = 0; e < 16; ++e) {
            const float* wp = wb + e * HID + h0;   // wave-uniform -> s_load
#pragma unroll
            for (int i = 0; i < 8; ++i)
                acc[e] = fmaf(av[i], wp[i], acc[e]);
        }
    }

    // each wave writes its own 16-expert column slice; banks: (lane+col)%32 -> 2/bank, free
#pragma unroll
    for (int e = 0; e < 16; ++e)
        lacc[trow][e0 + e] = acc[e] + bias[e0 + e];
    __syncthreads();

    // coalesced logits store: thread -> token tid>>2, 16-col quarter tid&3
    {
        const int t  = tid >> 2;
        const int c0 = (tid & 3) * 16;
        float* lp = logits + (size_t)(blockIdx.x * 128 + t) * NE + c0;
#pragma unroll
        for (int q = 0; q < 4; ++q)
            *(float4*)(lp + 4 * q) = make_float4(lacc[t][c0 + 4*q],     lacc[t][c0 + 4*q + 1],
                                                 lacc[t][c0 + 4*q + 2], lacc[t][c0 + 4*q + 3]);
    }

    // per-token epilogue (2 waves): top-2 + softmax denominator
    if (tid < 128) {
        const int t = tid;
        float m1 = -3.4e38f, m2 = -3.4e38f;
        int i1 = 0, i2 = 0;
#pragma unroll
        for (int e = 0; e < NE; ++e) {
            const float vv = lacc[t][e];
            if (vv > m1)      { m2 = m1; i2 = i1; m1 = vv; i1 = e; }
            else if (vv > m2) { m2 = vv; i2 = e; }
        }
        float s = 0.0f;
#pragma unroll
        for (int e = 0; e < NE; ++e)
            s += __expf(lacc[t][e] - m1);
        const int g2 = blockIdx.x * 128 + t;
        probsmax[g2] = 1.0f / s;       // max prob = exp(0)/sum
        choice[g2]   = i1;
        idx2o[g2]    = i2;
        gapo[g2]     = m1 - m2;
    }
}

// ---------------------------------------------------------------------------
// K1b: fp64 refinement of near-tie argmax (matches the f64 np reference).
// ---------------------------------------------------------------------------
__global__ void k_refine(const float* __restrict__ A, const float* __restrict__ W,
                         const float* __restrict__ bias,
                         int* __restrict__ choice, const int* __restrict__ idx2,
                         const float* __restrict__ gap)
{
    const int gt = blockIdx.x * blockDim.x + threadIdx.x;
    if (gt >= NTOK) return;
    if (!(gap[gt] < GAP_THR)) return;
    const int i1 = choice[gt], i2 = idx2[gt];
    if (i1 == i2) return;
    const float* a  = A + (size_t)gt * HID;
    const float* w1 = W + (size_t)i1 * HID;
    const float* w2 = W + (size_t)i2 * HID;
    double d1 = (double)bias[i1], d2 = (double)bias[i2];
    for (int h = 0; h < HID; ++h) {
        const double av = (double)a[h];
        d1 += av * (double)w1[h];
        d2 += av * (double)w2[h];
    }
    if (d2 > d1 || (d2 == d1 && i2 < i1)) choice[gt] = i2;
}

// ---------------------------------------------------------------------------
// K2: per-64-token-chunk histogram of expert choices (wave ballot).
// 512 chunks total; chunks never straddle groups (64 | 8192).
// ---------------------------------------------------------------------------
__global__ void k_count(const int* __restrict__ choice, int* __restrict__ cnt)
{
    const int lane  = threadIdx.x & 63;
    const int wave  = threadIdx.x >> 6;
    const int chunk = blockIdx.x * 4 + wave;   // 0..511
    const int gt    = chunk * 64 + lane;
    const int c     = choice[gt];
    int mycnt = 0;
#pragma unroll 1
    for (int e = 0; e < NE; ++e) {
        const unsigned long long m = __ballot(c == e);
        if (lane == e) mycnt = (int)__popcll(m);
    }
    cnt[chunk * 64 + lane] = mycnt;
}

// ---------------------------------------------------------------------------
// K3: exclusive scan of chunk histograms along the 128 chunks of each group.
// ---------------------------------------------------------------------------
__global__ void k_scan(const int* __restrict__ cnt, int* __restrict__ off)
{
    const int g = blockIdx.x;     // 0..3
    const int e = threadIdx.x;    // 0..63
    int run = 0;
    for (int c = 0; c < 128; ++c) {
        const int idx = (g * 128 + c) * 64 + e;
        const int v = cnt[idx];
        off[idx] = run;
        run += v;
    }
}

// ---------------------------------------------------------------------------
// K4: emit expert_index rows (0/1 as fp32) with capacity mask.
// priority = chunk_offset + in-chunk ballot prefix + 1  (inclusive cumsum).
// ---------------------------------------------------------------------------
__global__ void k_emit(const int* __restrict__ choice, const int* __restrict__ off,
                       float* __restrict__ eout)
{
    const int lane  = threadIdx.x & 63;
    const int wave  = threadIdx.x >> 6;
    const int chunk = blockIdx.x * 4 + wave;
    const int gt    = chunk * 64 + lane;
    const int c     = choice[gt];
    unsigned long long mymask = 0;
#pragma unroll 1
    for (int e = 0; e < NE; ++e) {
        const unsigned long long m = __ballot(c == e);
        if (c == e) mymask = m;
    }
    const int pre  = (int)__popcll(mymask & ((1ull << lane) - 1ull));
    const int base = off[chunk * 64 + c];
    const float val = (base + pre + 1 <= CAP) ? 1.0f : 0.0f;
    float* op = eout + (size_t)gt * NE;
#pragma unroll
    for (int i = 0; i < 16; ++i) {
        float4 v;
        v.x = (4*i+0 == c) ? val : 0.0f;
        v.y = (4*i+1 == c) ? val : 0.0f;
        v.z = (4*i+2 == c) ? val : 0.0f;
        v.w = (4*i+3 == c) ? val : 0.0f;
        ((float4*)op)[i] = v;
    }
}

// ---------------------------------------------------------------------------
extern "C" void kernel_launch(void* const* d_in, const int* in_sizes, int n_in,
                              void* d_out, int out_size, void* d_ws, size_t ws_size,
                              hipStream_t stream) {
    const float* A = (const float*)d_in[0];   // [4, 8192, 2048]
    const float* W = (const float*)d_in[1];   // [64, 2048]
    const float* b = (const float*)d_in[2];   // [64]

    float* out        = (float*)d_out;
    float* expert_out = out;                        // 2,097,152
    float* probsmax   = out + 2097152;              //    32,768
    float* logits     = out + 2097152 + 32768;      // 2,097,152

    char* ws    = (char*)d_ws;
    int*   choice = (int*)(ws);                 // 128 KB
    int*   idx2   = (int*)(ws + 131072);        // 128 KB
    float* gap    = (float*)(ws + 262144);      // 128 KB
    int*   cnt    = (int*)(ws + 393216);        // 128 KB
    int*   off    = (int*)(ws + 524288);        // 128 KB

    hipLaunchKernelGGL(k_logits, dim3(256), dim3(512), 0, stream,
                       A, W, b, logits, probsmax, choice, idx2, gap);
    hipLaunchKernelGGL(k_refine, dim3(128), dim3(256), 0, stream,
                       A, W, b, choice, idx2, gap);
    hipLaunchKernelGGL(k_count, dim3(128), dim3(256), 0, stream, choice, cnt);
    hipLaunchKernelGGL(k_scan, dim3(4), dim3(64), 0, stream, cnt, off);
    hipLaunchKernelGGL(k_emit, dim3(128), dim3(256), 0, stream, choice, off, expert_out);
}

// Round 3
// 369.371 us; speedup vs baseline: 1.9442x; 1.9442x over previous
//
#include <hip/hip_runtime.h>

#define HID 2048
#define NE 64
#define NTOK 32768        // GROUPS * TOKENS = 4 * 8192
#define CAP 160
#define GAP_THR 0.03f

// ---------------------------------------------------------------------------
// K1: logits GEMM + softmax-max + top-2.  Block = 512 thr = 8 waves, 64 tokens.
// A is LDS-staged in 64x128-float chunks (coalesced float4 global loads,
// XOR-swizzled layout -> even 8/bank on the lane=row compute reads).
// Wave w owns expert octant e0 = w*8 (acc[8], static indexing, no spill).
// W addresses are wave-uniform via readfirstlane -> s_load (SMEM pipe).
// ---------------------------------------------------------------------------
__global__ __launch_bounds__(512) void k_logits(
    const float* __restrict__ A, const float* __restrict__ W,
    const float* __restrict__ bias,
    float* __restrict__ logits, float* __restrict__ probsmax,
    int* __restrict__ choice, int* __restrict__ idx2o, float* __restrict__ gapo)
{
    __shared__ float smem[8192];              // A-tile [64][128] swizzled; later lacc
    float (*lacc)[65] = (float(*)[65])smem;   // 64*65 = 4160 <= 8192

    const int tid  = threadIdx.x;
    const int lane = tid & 63;
    const int wv   = __builtin_amdgcn_readfirstlane(tid >> 6);  // 0..7 uniform
    const int e0   = wv * 8;
    const int tok0 = blockIdx.x * 64;

    const float* wb = W + (size_t)e0 * HID;

    float acc[8];
#pragma unroll
    for (int e = 0; e < 8; ++e) acc[e] = 0.0f;

#pragma unroll 1
    for (int ch = 0; ch < 16; ++ch) {
        __syncthreads();                      // previous chunk fully consumed
        // ---- stage: 64 rows x 128 floats, coalesced, swizzled ----
#pragma unroll
        for (int k = 0; k < 4; ++k) {
            const int f   = tid + 512 * k;    // float4 slot 0..2047
            const int row = f >> 5;           // 32 float4 per row
            const int c4  = f & 31;
            const float4 v = *(const float4*)(A + (size_t)(tok0 + row) * HID
                                              + ch * 128 + c4 * 4);
            const int dw = row * 128 + ((c4 * 4) ^ ((row & 7) << 2));
            *(float4*)(smem + dw) = v;
        }
        __syncthreads();
        // ---- compute: 16 steps of 8 h-values ----
#pragma unroll 2
        for (int s = 0; s < 16; ++s) {
            const int cda = (8 * s)     ^ ((lane & 7) << 2);
            const int cdb = (8 * s + 4) ^ ((lane & 7) << 2);
            const float4 va = *(const float4*)(smem + lane * 128 + cda);
            const float4 vb = *(const float4*)(smem + lane * 128 + cdb);
            const float av[8] = {va.x, va.y, va.z, va.w, vb.x, vb.y, vb.z, vb.w};
            const int hoff = ch * 128 + s * 8;
#pragma unroll
            for (int e = 0; e < 8; ++e) {
                const float* wp = wb + e * HID + hoff;   // uniform -> s_load
#pragma unroll
                for (int i = 0; i < 8; ++i)
                    acc[e] = fmaf(av[i], wp[i], acc[e]);
            }
        }
    }
    __syncthreads();                          // done reading A tile

    // exchange: wave wv supplies experts e0..e0+7 for token=lane
#pragma unroll
    for (int e = 0; e < 8; ++e)
        lacc[lane][e0 + e] = acc[e] + bias[e0 + e];
    __syncthreads();

    // coalesced logits store: thread -> token tid>>3, 8-col slice (tid&7)*8
    {
        const int t  = tid >> 3;
        const int c8 = (tid & 7) * 8;
        float* lp = logits + (size_t)(tok0 + t) * NE + c8;
        *(float4*)(lp)     = make_float4(lacc[t][c8],     lacc[t][c8 + 1],
                                         lacc[t][c8 + 2], lacc[t][c8 + 3]);
        *(float4*)(lp + 4) = make_float4(lacc[t][c8 + 4], lacc[t][c8 + 5],
                                         lacc[t][c8 + 6], lacc[t][c8 + 7]);
    }

    // per-token epilogue (wave 0): top-2 + softmax denominator
    if (tid < 64) {
        const int t = tid;
        float m1 = -3.4e38f, m2 = -3.4e38f;
        int i1 = 0, i2 = 0;
#pragma unroll
        for (int e = 0; e < NE; ++e) {
            const float vv = lacc[t][e];
            if (vv > m1)      { m2 = m1; i2 = i1; m1 = vv; i1 = e; }
            else if (vv > m2) { m2 = vv; i2 = e; }
        }
        float s = 0.0f;
#pragma unroll
        for (int e = 0; e < NE; ++e)
            s += __expf(lacc[t][e] - m1);
        const int g2 = tok0 + t;
        probsmax[g2] = 1.0f / s;       // max prob = exp(0)/sum
        choice[g2]   = i1;
        idx2o[g2]    = i2;
        gapo[g2]     = m1 - m2;
    }
}

// ---------------------------------------------------------------------------
// K1b: fp64 refinement of near-tie argmax (matches the f64/np reference).
// ---------------------------------------------------------------------------
__global__ void k_refine(const float* __restrict__ A, const float* __restrict__ W,
                         const float* __restrict__ bias,
                         int* __restrict__ choice, const int* __restrict__ idx2,
                         const float* __restrict__ gap)
{
    const int gt = blockIdx.x * blockDim.x + threadIdx.x;
    if (gt >= NTOK) return;
    if (!(gap[gt] < GAP_THR)) return;
    const int i1 = choice[gt], i2 = idx2[gt];
    if (i1 == i2) return;
    const float* a  = A + (size_t)gt * HID;
    const float* w1 = W + (size_t)i1 * HID;
    const float* w2 = W + (size_t)i2 * HID;
    double d1 = (double)bias[i1], d2 = (double)bias[i2];
    for (int h = 0; h < HID; ++h) {
        const double av = (double)a[h];
        d1 += av * (double)w1[h];
        d2 += av * (double)w2[h];
    }
    if (d2 > d1 || (d2 == d1 && i2 < i1)) choice[gt] = i2;
}

// ---------------------------------------------------------------------------
// K2: per-64-token-chunk histogram of expert choices (wave ballot).
// ---------------------------------------------------------------------------
__global__ void k_count(const int* __restrict__ choice, int* __restrict__ cnt)
{
    const int lane  = threadIdx.x & 63;
    const int wave  = threadIdx.x >> 6;
    const int chunk = blockIdx.x * 4 + wave;   // 0..511
    const int gt    = chunk * 64 + lane;
    const int c     = choice[gt];
    int mycnt = 0;
#pragma unroll 1
    for (int e = 0; e < NE; ++e) {
        const unsigned long long m = __ballot(c == e);
        if (lane == e) mycnt = (int)__popcll(m);
    }
    cnt[chunk * 64 + lane] = mycnt;
}

// ---------------------------------------------------------------------------
// K3: exclusive scan of chunk histograms along the 128 chunks of each group.
// ---------------------------------------------------------------------------
__global__ void k_scan(const int* __restrict__ cnt, int* __restrict__ off)
{
    const int g = blockIdx.x;     // 0..3
    const int e = threadIdx.x;    // 0..63
    int run = 0;
    for (int c = 0; c < 128; ++c) {
        const int idx = (g * 128 + c) * 64 + e;
        const int v = cnt[idx];
        off[idx] = run;
        run += v;
    }
}

// ---------------------------------------------------------------------------
// K4: emit expert_index rows (0/1 as fp32) with capacity mask.
// ---------------------------------------------------------------------------
__global__ void k_emit(const int* __restrict__ choice, const int* __restrict__ off,
                       float* __restrict__ eout)
{
    const int lane  = threadIdx.x & 63;
    const int wave  = threadIdx.x >> 6;
    const int chunk = blockIdx.x * 4 + wave;
    const int gt    = chunk * 64 + lane;
    const int c     = choice[gt];
    unsigned long long mymask = 0;
#pragma unroll 1
    for (int e = 0; e < NE; ++e) {
        const unsigned long long m = __ballot(c == e);
        if (c == e) mymask = m;
    }
    const int pre  = (int)__popcll(mymask & ((1ull << lane) - 1ull));
    const int base = off[chunk * 64 + c];
    const float val = (base + pre + 1 <= CAP) ? 1.0f : 0.0f;
    float* op = eout + (size_t)gt * NE;
#pragma unroll
    for (int i = 0; i < 16; ++i) {
        float4 v;
        v.x = (4*i+0 == c) ? val : 0.0f;
        v.y = (4*i+1 == c) ? val : 0.0f;
        v.z = (4*i+2 == c) ? val : 0.0f;
        v.w = (4*i+3 == c) ? val : 0.0f;
        ((float4*)op)[i] = v;
    }
}

// ---------------------------------------------------------------------------
extern "C" void kernel_launch(void* const* d_in, const int* in_sizes, int n_in,
                              void* d_out, int out_size, void* d_ws, size_t ws_size,
                              hipStream_t stream) {
    const float* A = (const float*)d_in[0];   // [4, 8192, 2048]
    const float* W = (const float*)d_in[1];   // [64, 2048]
    const float* b = (const float*)d_in[2];   // [64]

    float* out        = (float*)d_out;
    float* expert_out = out;                        // 2,097,152
    float* probsmax   = out + 2097152;              //    32,768
    float* logits     = out + 2097152 + 32768;      // 2,097,152

    char* ws    = (char*)d_ws;
    int*   choice = (int*)(ws);                 // 128 KB
    int*   idx2   = (int*)(ws + 131072);        // 128 KB
    float* gap    = (float*)(ws + 262144);      // 128 KB
    int*   cnt    = (int*)(ws + 393216);        // 128 KB
    int*   off    = (int*)(ws + 524288);        // 128 KB

    hipLaunchKernelGGL(k_logits, dim3(512), dim3(512), 0, stream,
                       A, W, b, logits, probsmax, choice, idx2, gap);
    hipLaunchKernelGGL(k_refine, dim3(128), dim3(256), 0, stream,
                       A, W, b, choice, idx2, gap);
    hipLaunchKernelGGL(k_count, dim3(128), dim3(256), 0, stream, choice, cnt);
    hipLaunchKernelGGL(k_scan, dim3(4), dim3(64), 0, stream, cnt, off);
    hipLaunchKernelGGL(k_emit, dim3(128), dim3(256), 0, stream, choice, off, expert_out);
}

// Round 4
// 261.102 us; speedup vs baseline: 2.7503x; 1.4147x over previous
//
#include <hip/hip_runtime.h>

#define HID 2048
#define NE 64
#define NTOK 32768        // GROUPS * TOKENS = 4 * 8192
#define CAP 160
#define GAP_THR 0.01f

typedef unsigned short u16;
typedef short bf16x8 __attribute__((ext_vector_type(8)));
typedef float f32x16 __attribute__((ext_vector_type(16)));

// fp32 -> bf16 hi (truncate) + bf16 lo (truncate of exact remainder).
// hi+lo carries ~16 mantissa bits; 3-term MFMA error ~2e-5 per product.
static __device__ __forceinline__ void cvt8(const float4& a, const float4& b,
                                            bf16x8& hi, bf16x8& lo) {
    float f[8] = {a.x, a.y, a.z, a.w, b.x, b.y, b.z, b.w};
#pragma unroll
    for (int j = 0; j < 8; ++j) {
        const unsigned u = __float_as_uint(f[j]);
        const unsigned h = u >> 16;
        const float r = f[j] - __uint_as_float(h << 16);   // exact
        const unsigned l = __float_as_uint(r) >> 16;
        hi[j] = (short)h;
        lo[j] = (short)l;
    }
}

// ---------------------------------------------------------------------------
// K0: split W into bf16 hi/lo planes (runs once per call; 512KB read, trivial)
// ---------------------------------------------------------------------------
__global__ void k_wconv(const float* __restrict__ W,
                        u16* __restrict__ Whi, u16* __restrict__ Wlo)
{
    const int i = blockIdx.x * 256 + threadIdx.x;
    if (i < NE * HID) {
        const float f = W[i];
        const unsigned u = __float_as_uint(f);
        const unsigned h = u >> 16;
        const float r = f - __uint_as_float(h << 16);
        Whi[i] = (u16)h;
        Wlo[i] = (u16)(__float_as_uint(r) >> 16);
    }
}

// ---------------------------------------------------------------------------
// K1: logits via 3-term bf16-split MFMA. Block = 256 thr = 4 waves.
// All 4 waves: same 32 tokens; wave kq owns K-quarter [kq*512, +512).
// MFMA 32x32x16: A-operand = W (32 experts x 16k, lane&31=expert, k=(lane>>5)*8+j),
// B-operand = tokens (lane&31=token). C: col(lane&31)=token,
// row=(r&3)+8*(r>>2)+4*(lane>>5)=expert  [m74/m101-verified layout].
// A fp32 loaded per-lane (32B, fully consumed), cvt in-reg; no LDS in K-loop.
// ---------------------------------------------------------------------------
__global__ __launch_bounds__(256, 4) void k_logits(
    const float* __restrict__ A, const u16* __restrict__ Whi,
    const u16* __restrict__ Wlo, const float* __restrict__ bias,
    float* __restrict__ logits, float* __restrict__ probsmax,
    int* __restrict__ choice, int* __restrict__ idx2o, float* __restrict__ gapo)
{
    __shared__ float lds[4 * 32 * 65];    // [kq][token][65] (pad 65: conflict-free)
    const int tid  = threadIdx.x;
    const int lane = tid & 63;
    const int kq   = __builtin_amdgcn_readfirstlane(tid >> 6);  // 0..3 uniform
    const int tok0 = blockIdx.x * 32;
    const int trow = lane & 31;           // token (B-col) / expert (A-row)
    const int khal = lane >> 5;           // k-half selector

    const float* abase = A + (size_t)(tok0 + trow) * HID + kq * 512 + khal * 8;
    const size_t woff  = (size_t)trow * HID + kq * 512 + khal * 8;
    const u16* wh0p = Whi + woff;
    const u16* wh1p = wh0p + 32 * HID;
    const u16* wl0p = Wlo + woff;
    const u16* wl1p = wl0p + 32 * HID;

    f32x16 acc0, acc1;
#pragma unroll
    for (int r = 0; r < 16; ++r) { acc0[r] = 0.0f; acc1[r] = 0.0f; }

    float4 p0a, p0b, p1a, p1b, p2a, p2b, p3a, p3b;   // 4-deep A prefetch

#define LOADA(P, KS) { P##a = *(const float4*)(abase + (KS) * 16);     \
                       P##b = *(const float4*)(abase + (KS) * 16 + 4); }
#define MFMA_ __builtin_amdgcn_mfma_f32_32x32x16_bf16
#define STEP(P, KS, DO_RELOAD, KS2) {                                   \
    const bf16x8 wh0 = *(const bf16x8*)(wh0p + (KS) * 16);              \
    const bf16x8 wh1 = *(const bf16x8*)(wh1p + (KS) * 16);              \
    const bf16x8 wl0 = *(const bf16x8*)(wl0p + (KS) * 16);              \
    const bf16x8 wl1 = *(const bf16x8*)(wl1p + (KS) * 16);              \
    bf16x8 ah, al; cvt8(P##a, P##b, ah, al);                            \
    if (DO_RELOAD) LOADA(P, KS2)                                        \
    acc0 = MFMA_(wh0, ah, acc0, 0, 0, 0);                               \
    acc1 = MFMA_(wh1, ah, acc1, 0, 0, 0);                               \
    acc0 = MFMA_(wl0, ah, acc0, 0, 0, 0);                               \
    acc1 = MFMA_(wl1, ah, acc1, 0, 0, 0);                               \
    acc0 = MFMA_(wh0, al, acc0, 0, 0, 0);                               \
    acc1 = MFMA_(wh1, al, acc1, 0, 0, 0);                               \
}

    LOADA(p0, 0) LOADA(p1, 1) LOADA(p2, 2) LOADA(p3, 3)
#pragma unroll 1
    for (int ks = 0; ks < 28; ks += 4) {
        STEP(p0, ks + 0, 1, ks + 4)
        STEP(p1, ks + 1, 1, ks + 5)
        STEP(p2, ks + 2, 1, ks + 6)
        STEP(p3, ks + 3, 1, ks + 7)
    }
    STEP(p0, 28, 0, 0) STEP(p1, 29, 0, 0) STEP(p2, 30, 0, 0) STEP(p3, 31, 0, 0)
#undef STEP
#undef LOADA

    // C -> LDS: token = lane&31 (col), expert = (r&3)+8*(r>>2)+4*khal (row)
    {
        float* pl = lds + kq * 2080 + trow * 65;
#pragma unroll
        for (int r = 0; r < 16; ++r) {
            const int er = (r & 3) + 8 * (r >> 2) + 4 * khal;
            pl[er]      = acc0[r];
            pl[32 + er] = acc1[r];
        }
    }
    __syncthreads();

    // split-K reduce (+bias), coalesced logits store, stash row into plane 0
    {
        const int t  = tid >> 3;          // 0..31
        const int e0 = (tid & 7) * 8;
        float v[8];
#pragma unroll
        for (int i = 0; i < 8; ++i) {
            const int o = t * 65 + e0 + i;
            v[i] = lds[o] + lds[2080 + o] + lds[4160 + o] + lds[6240 + o]
                 + bias[e0 + i];
        }
        float* lp = logits + (size_t)(tok0 + t) * NE + e0;
        *(float4*)(lp)     = make_float4(v[0], v[1], v[2], v[3]);
        *(float4*)(lp + 4) = make_float4(v[4], v[5], v[6], v[7]);
#pragma unroll
        for (int i = 0; i < 8; ++i) lds[t * 65 + e0 + i] = v[i];
    }
    __syncthreads();

    // per-token epilogue: top-2 + softmax denominator
    if (tid < 32) {
        const int t = tid;
        float m1 = -3.4e38f, m2 = -3.4e38f;
        int i1 = 0, i2 = 0;
#pragma unroll
        for (int e = 0; e < NE; ++e) {
            const float vv = lds[t * 65 + e];
            if (vv > m1)      { m2 = m1; i2 = i1; m1 = vv; i1 = e; }
            else if (vv > m2) { m2 = vv; i2 = e; }
        }
        float s = 0.0f;
#pragma unroll
        for (int e = 0; e < NE; ++e)
            s += __expf(lds[t * 65 + e] - m1);
        const int g2 = tok0 + t;
        probsmax[g2] = 1.0f / s;          // max prob = exp(0)/sum
        choice[g2]   = i1;
        idx2o[g2]    = i2;
        gapo[g2]     = m1 - m2;
    }
}

// ---------------------------------------------------------------------------
// K1b: fp64 refinement of near-tie argmax (matches the f64/np reference).
// ---------------------------------------------------------------------------
__global__ void k_refine(const float* __restrict__ A, const float* __restrict__ W,
                         const float* __restrict__ bias,
                         int* __restrict__ choice, const int* __restrict__ idx2,
                         const float* __restrict__ gap)
{
    const int gt = blockIdx.x * blockDim.x + threadIdx.x;
    if (gt >= NTOK) return;
    if (!(gap[gt] < GAP_THR)) return;
    const int i1 = choice[gt], i2 = idx2[gt];
    if (i1 == i2) return;
    const float* a  = A + (size_t)gt * HID;
    const float* w1 = W + (size_t)i1 * HID;
    const float* w2 = W + (size_t)i2 * HID;
    double d1 = (double)bias[i1], d2 = (double)bias[i2];
    for (int h = 0; h < HID; ++h) {
        const double av = (double)a[h];
        d1 += av * (double)w1[h];
        d2 += av * (double)w2[h];
    }
    if (d2 > d1 || (d2 == d1 && i2 < i1)) choice[gt] = i2;
}

// ---------------------------------------------------------------------------
// K2: per-64-token-chunk histogram of expert choices (wave ballot).
// ---------------------------------------------------------------------------
__global__ void k_count(const int* __restrict__ choice, int* __restrict__ cnt)
{
    const int lane  = threadIdx.x & 63;
    const int wave  = threadIdx.x >> 6;
    const int chunk = blockIdx.x * 4 + wave;   // 0..511
    const int gt    = chunk * 64 + lane;
    const int c     = choice[gt];
    int mycnt = 0;
#pragma unroll 1
    for (int e = 0; e < NE; ++e) {
        const unsigned long long m = __ballot(c == e);
        if (lane == e) mycnt = (int)__popcll(m);
    }
    cnt[chunk * 64 + lane] = mycnt;
}

// ---------------------------------------------------------------------------
// K3: exclusive scan of chunk histograms along the 128 chunks of each group.
// ---------------------------------------------------------------------------
__global__ void k_scan(const int* __restrict__ cnt, int* __restrict__ off)
{
    const int g = blockIdx.x;     // 0..3
    const int e = threadIdx.x;    // 0..63
    int run = 0;
    for (int c = 0; c < 128; ++c) {
        const int idx = (g * 128 + c) * 64 + e;
        const int v = cnt[idx];
        off[idx] = run;
        run += v;
    }
}

// ---------------------------------------------------------------------------
// K4: emit expert_index rows (0/1 as fp32) with capacity mask.
// ---------------------------------------------------------------------------
__global__ void k_emit(const int* __restrict__ choice, const int* __restrict__ off,
                       float* __restrict__ eout)
{
    const int lane  = threadIdx.x & 63;
    const int wave  = threadIdx.x >> 6;
    const int chunk = blockIdx.x * 4 + wave;
    const int gt    = chunk * 64 + lane;
    const int c     = choice[gt];
    unsigned long long mymask = 0;
#pragma unroll 1
    for (int e = 0; e < NE; ++e) {
        const unsigned long long m = __ballot(c == e);
        if (c == e) mymask = m;
    }
    const int pre  = (int)__popcll(mymask & ((1ull << lane) - 1ull));
    const int base = off[chunk * 64 + c];
    const float val = (base + pre + 1 <= CAP) ? 1.0f : 0.0f;
    float* op = eout + (size_t)gt * NE;
#pragma unroll
    for (int i = 0; i < 16; ++i) {
        float4 v;
        v.x = (4*i+0 == c) ? val : 0.0f;
        v.y = (4*i+1 == c) ? val : 0.0f;
        v.z = (4*i+2 == c) ? val : 0.0f;
        v.w = (4*i+3 == c) ? val : 0.0f;
        ((float4*)op)[i] = v;
    }
}

// ---------------------------------------------------------------------------
extern "C" void kernel_launch(void* const* d_in, const int* in_sizes, int n_in,
                              void* d_out, int out_size, void* d_ws, size_t ws_size,
                              hipStream_t stream) {
    const float* A = (const float*)d_in[0];   // [4, 8192, 2048]
    const float* W = (const float*)d_in[1];   // [64, 2048]
    const float* b = (const float*)d_in[2];   // [64]

    float* out        = (float*)d_out;
    float* expert_out = out;                        // 2,097,152
    float* probsmax   = out + 2097152;              //    32,768
    float* logits     = out + 2097152 + 32768;      // 2,097,152

    char* ws      = (char*)d_ws;
    int*   choice = (int*)(ws);                 // 128 KB
    int*   idx2   = (int*)(ws + 131072);        // 128 KB
    float* gap    = (float*)(ws + 262144);      // 128 KB
    int*   cnt    = (int*)(ws + 393216);        // 128 KB
    int*   off    = (int*)(ws + 524288);        // 128 KB
    u16*   Whi    = (u16*)(ws + 655360);        // 256 KB
    u16*   Wlo    = (u16*)(ws + 917504);        // 256 KB

    hipLaunchKernelGGL(k_wconv, dim3(512), dim3(256), 0, stream, W, Whi, Wlo);
    hipLaunchKernelGGL(k_logits, dim3(1024), dim3(256), 0, stream,
                       A, Whi, Wlo, b, logits, probsmax, choice, idx2, gap);
    hipLaunchKernelGGL(k_refine, dim3(128), dim3(256), 0, stream,
                       A, W, b, choice, idx2, gap);
    hipLaunchKernelGGL(k_count, dim3(128), dim3(256), 0, stream, choice, cnt);
    hipLaunchKernelGGL(k_scan, dim3(4), dim3(64), 0, stream, cnt, off);
    hipLaunchKernelGGL(k_emit, dim3(128), dim3(256), 0, stream, choice, off, expert_out);
}

// Round 5
// 204.685 us; speedup vs baseline: 3.5084x; 1.2756x over previous
//
#include <hip/hip_runtime.h>

#define HID 2048
#define NE 64
#define NTOK 32768        // GROUPS * TOKENS = 4 * 8192
#define CAP 160
#define GAP_THR 0.01f

typedef unsigned short u16;
typedef short bf16x8 __attribute__((ext_vector_type(8)));
typedef float f32x16 __attribute__((ext_vector_type(16)));

// fp32 -> bf16 hi (truncate) + bf16 lo (truncate of exact remainder).
static __device__ __forceinline__ void cvt8(const float4& a, const float4& b,
                                            bf16x8& hi, bf16x8& lo) {
    float f[8] = {a.x, a.y, a.z, a.w, b.x, b.y, b.z, b.w};
#pragma unroll
    for (int j = 0; j < 8; ++j) {
        const unsigned u = __float_as_uint(f[j]);
        const unsigned h = u >> 16;
        const float r = f[j] - __uint_as_float(h << 16);   // exact
        hi[j] = (short)h;
        lo[j] = (short)(__float_as_uint(r) >> 16);
    }
}

// ---------------------------------------------------------------------------
// K0: split W into bf16 hi/lo and store in MFMA fragment-major order.
// Step S = kq*32+ks owns 4 KB: chunks [h0|h1|l0|l1], each 1 KB = lane*8 u16.
// Chunk c, lane l holds expert e=(c&1)*32+(l&31), k=kq*512+ks*16+(l>>5)*8+j.
// K-loop W reads become uniform_base + lane*16B: fully coalesced + sequential.
// ---------------------------------------------------------------------------
__global__ void k_wconv(const float* __restrict__ W, u16* __restrict__ Wfrag)
{
    const int idx = blockIdx.x * 256 + threadIdx.x;   // 0..16383
    if (idx >= NE * (HID / 8)) return;
    const int e  = idx >> 8;          // expert 0..63
    const int k8 = idx & 255;         // 8-float chunk 0..255
    const int k0 = k8 * 8;
    const int kq   = k0 >> 9;
    const int kk   = k0 & 511;
    const int ks   = kk >> 4;
    const int khal = (kk >> 3) & 1;
    const int lane = (e & 31) + khal * 32;
    const int S    = kq * 32 + ks;

    bf16x8 hi, lo;
    const float4 a = *(const float4*)(W + (size_t)e * HID + k0);
    const float4 b = *(const float4*)(W + (size_t)e * HID + k0 + 4);
    cvt8(a, b, hi, lo);

    u16* base = Wfrag + (size_t)S * 2048 + (size_t)(e >> 5) * 512 + lane * 8;
    *(bf16x8*)(base)        = hi;     // chunk (e>>5)
    *(bf16x8*)(base + 1024) = lo;     // chunk 2+(e>>5)
}

// ---------------------------------------------------------------------------
// K1: logits via 3-term bf16-split MFMA. Block = 256 thr = 4 waves.
// All 4 waves: same 32 tokens; wave kq owns K-quarter [kq*512, +512).
// A-operand = W experts (lane&31=expert), B-operand = tokens (lane&31=token).
// C: col(lane&31)=token, row=(r&3)+8*(r>>2)+4*(lane>>5)=expert.
// Both streams software-pipelined 2 K-steps deep; W reads are coalesced
// contiguous (fragment-major Wfrag), A reads are per-token 32B gathers.
// ---------------------------------------------------------------------------
__global__ __launch_bounds__(256, 4) void k_logits(
    const float* __restrict__ A, const u16* __restrict__ Wfrag,
    const float* __restrict__ bias,
    float* __restrict__ logits, float* __restrict__ probsmax,
    int* __restrict__ choice, int* __restrict__ idx2o, float* __restrict__ gapo)
{
    __shared__ float lds[4 * 32 * 65];    // [kq][token][65] (pad: conflict-free)
    const int tid  = threadIdx.x;
    const int lane = tid & 63;
    const int kq   = __builtin_amdgcn_readfirstlane(tid >> 6);  // 0..3 uniform
    const int tok0 = blockIdx.x * 32;
    const int trow = lane & 31;           // token (B-col) / expert (A-row)
    const int khal = lane >> 5;

    const float* abase = A + (size_t)(tok0 + trow) * HID + kq * 512 + khal * 8;
    const u16*   wbase = Wfrag + (size_t)(kq * 32) * 2048 + lane * 8;

    f32x16 acc0, acc1;
#pragma unroll
    for (int r = 0; r < 16; ++r) { acc0[r] = 0.0f; acc1[r] = 0.0f; }

    float4 p0a, p0b, p1a, p1b;
    bf16x8 w0h0, w0h1, w0l0, w0l1, w1h0, w1h1, w1l0, w1l1;

#define LOADA(P, KS) { P##a = *(const float4*)(abase + (KS) * 16);      \
                       P##b = *(const float4*)(abase + (KS) * 16 + 4); }
#define LOADW(G, KS) { const u16* wp = wbase + (size_t)(KS) * 2048;     \
                       G##h0 = *(const bf16x8*)(wp);                    \
                       G##h1 = *(const bf16x8*)(wp + 512);              \
                       G##l0 = *(const bf16x8*)(wp + 1024);             \
                       G##l1 = *(const bf16x8*)(wp + 1536); }
#define MFMA_ __builtin_amdgcn_mfma_f32_32x32x16_bf16
// Issue next loads FIRST (max distance), then consume current regs.
#define STEP(P, G, R, KS) {                                             \
    float4 na, nb; bf16x8 nh0, nh1, nl0, nl1;                           \
    if (R) { na = *(const float4*)(abase + (KS) * 16);                  \
             nb = *(const float4*)(abase + (KS) * 16 + 4);              \
             const u16* wp = wbase + (size_t)(KS) * 2048;               \
             nh0 = *(const bf16x8*)(wp);                                \
             nh1 = *(const bf16x8*)(wp + 512);                          \
             nl0 = *(const bf16x8*)(wp + 1024);                         \
             nl1 = *(const bf16x8*)(wp + 1536); }                       \
    bf16x8 ah, al; cvt8(P##a, P##b, ah, al);                            \
    acc0 = MFMA_(G##h0, ah, acc0, 0, 0, 0);                             \
    acc1 = MFMA_(G##h1, ah, acc1, 0, 0, 0);                             \
    acc0 = MFMA_(G##l0, ah, acc0, 0, 0, 0);                             \
    acc1 = MFMA_(G##l1, ah, acc1, 0, 0, 0);                             \
    acc0 = MFMA_(G##h0, al, acc0, 0, 0, 0);                             \
    acc1 = MFMA_(G##h1, al, acc1, 0, 0, 0);                             \
    if (R) { P##a = na; P##b = nb;                                      \
             G##h0 = nh0; G##h1 = nh1; G##l0 = nl0; G##l1 = nl1; }      \
}

    LOADA(p0, 0) LOADA(p1, 1) LOADW(w0, 0) LOADW(w1, 1)
#pragma unroll 1
    for (int ks = 0; ks < 30; ks += 2) {
        STEP(p0, w0, 1, ks + 2)
        STEP(p1, w1, 1, ks + 3)
    }
    STEP(p0, w0, 0, 0)
    STEP(p1, w1, 0, 0)
#undef STEP
#undef LOADA
#undef LOADW

    // C -> LDS: token = lane&31 (col), expert = (r&3)+8*(r>>2)+4*khal (row)
    {
        float* pl = lds + kq * 2080 + trow * 65;
#pragma unroll
        for (int r = 0; r < 16; ++r) {
            const int er = (r & 3) + 8 * (r >> 2) + 4 * khal;
            pl[er]      = acc0[r];
            pl[32 + er] = acc1[r];
        }
    }
    __syncthreads();

    // split-K reduce (+bias), coalesced logits store, stash row into plane 0
    {
        const int t  = tid >> 3;          // 0..31
        const int e0 = (tid & 7) * 8;
        float v[8];
#pragma unroll
        for (int i = 0; i < 8; ++i) {
            const int o = t * 65 + e0 + i;
            v[i] = lds[o] + lds[2080 + o] + lds[4160 + o] + lds[6240 + o]
                 + bias[e0 + i];
        }
        float* lp = logits + (size_t)(tok0 + t) * NE + e0;
        *(float4*)(lp)     = make_float4(v[0], v[1], v[2], v[3]);
        *(float4*)(lp + 4) = make_float4(v[4], v[5], v[6], v[7]);
#pragma unroll
        for (int i = 0; i < 8; ++i) lds[t * 65 + e0 + i] = v[i];
    }
    __syncthreads();

    // per-token epilogue: top-2 + softmax denominator
    if (tid < 32) {
        const int t = tid;
        float m1 = -3.4e38f, m2 = -3.4e38f;
        int i1 = 0, i2 = 0;
#pragma unroll
        for (int e = 0; e < NE; ++e) {
            const float vv = lds[t * 65 + e];
            if (vv > m1)      { m2 = m1; i2 = i1; m1 = vv; i1 = e; }
            else if (vv > m2) { m2 = vv; i2 = e; }
        }
        float s = 0.0f;
#pragma unroll
        for (int e = 0; e < NE; ++e)
            s += __expf(lds[t * 65 + e] - m1);
        const int g2 = tok0 + t;
        probsmax[g2] = 1.0f / s;          // max prob = exp(0)/sum
        choice[g2]   = i1;
        idx2o[g2]    = i2;
        gapo[g2]     = m1 - m2;
    }
}

// ---------------------------------------------------------------------------
// K1b: fp64 refinement of near-tie argmax (matches the f64/np reference).
// ---------------------------------------------------------------------------
__global__ void k_refine(const float* __restrict__ A, const float* __restrict__ W,
                         const float* __restrict__ bias,
                         int* __restrict__ choice, const int* __restrict__ idx2,
                         const float* __restrict__ gap)
{
    const int gt = blockIdx.x * blockDim.x + threadIdx.x;
    if (gt >= NTOK) return;
    if (!(gap[gt] < GAP_THR)) return;
    const int i1 = choice[gt], i2 = idx2[gt];
    if (i1 == i2) return;
    const float* a  = A + (size_t)gt * HID;
    const float* w1 = W + (size_t)i1 * HID;
    const float* w2 = W + (size_t)i2 * HID;
    double d1 = (double)bias[i1], d2 = (double)bias[i2];
    for (int h = 0; h < HID; ++h) {
        const double av = (double)a[h];
        d1 += av * (double)w1[h];
        d2 += av * (double)w2[h];
    }
    if (d2 > d1 || (d2 == d1 && i2 < i1)) choice[gt] = i2;
}

// ---------------------------------------------------------------------------
// K2: per-64-token-chunk histogram of expert choices (wave ballot).
// ---------------------------------------------------------------------------
__global__ void k_count(const int* __restrict__ choice, int* __restrict__ cnt)
{
    const int lane  = threadIdx.x & 63;
    const int wave  = threadIdx.x >> 6;
    const int chunk = blockIdx.x * 4 + wave;   // 0..511
    const int gt    = chunk * 64 + lane;
    const int c     = choice[gt];
    int mycnt = 0;
#pragma unroll 1
    for (int e = 0; e < NE; ++e) {
        const unsigned long long m = __ballot(c == e);
        if (lane == e) mycnt = (int)__popcll(m);
    }
    cnt[chunk * 64 + lane] = mycnt;
}

// ---------------------------------------------------------------------------
// K3: exclusive scan of chunk histograms along the 128 chunks of each group.
// ---------------------------------------------------------------------------
__global__ void k_scan(const int* __restrict__ cnt, int* __restrict__ off)
{
    const int g = blockIdx.x;     // 0..3
    const int e = threadIdx.x;    // 0..63
    int run = 0;
    for (int c = 0; c < 128; ++c) {
        const int idx = (g * 128 + c) * 64 + e;
        const int v = cnt[idx];
        off[idx] = run;
        run += v;
    }
}

// ---------------------------------------------------------------------------
// K4: emit expert_index rows (0/1 as fp32) with capacity mask.
// ---------------------------------------------------------------------------
__global__ void k_emit(const int* __restrict__ choice, const int* __restrict__ off,
                       float* __restrict__ eout)
{
    const int lane  = threadIdx.x & 63;
    const int wave  = threadIdx.x >> 6;
    const int chunk = blockIdx.x * 4 + wave;
    const int gt    = chunk * 64 + lane;
    const int c     = choice[gt];
    unsigned long long mymask = 0;
#pragma unroll 1
    for (int e = 0; e < NE; ++e) {
        const unsigned long long m = __ballot(c == e);
        if (c == e) mymask = m;
    }
    const int pre  = (int)__popcll(mymask & ((1ull << lane) - 1ull));
    const int base = off[chunk * 64 + c];
    const float val = (base + pre + 1 <= CAP) ? 1.0f : 0.0f;
    float* op = eout + (size_t)gt * NE;
#pragma unroll
    for (int i = 0; i < 16; ++i) {
        float4 v;
        v.x = (4*i+0 == c) ? val : 0.0f;
        v.y = (4*i+1 == c) ? val : 0.0f;
        v.z = (4*i+2 == c) ? val : 0.0f;
        v.w = (4*i+3 == c) ? val : 0.0f;
        ((float4*)op)[i] = v;
    }
}

// ---------------------------------------------------------------------------
extern "C" void kernel_launch(void* const* d_in, const int* in_sizes, int n_in,
                              void* d_out, int out_size, void* d_ws, size_t ws_size,
                              hipStream_t stream) {
    const float* A = (const float*)d_in[0];   // [4, 8192, 2048]
    const float* W = (const float*)d_in[1];   // [64, 2048]
    const float* b = (const float*)d_in[2];   // [64]

    float* out        = (float*)d_out;
    float* expert_out = out;                        // 2,097,152
    float* probsmax   = out + 2097152;              //    32,768
    float* logits     = out + 2097152 + 32768;      // 2,097,152

    char* ws      = (char*)d_ws;
    int*   choice = (int*)(ws);                 // 128 KB
    int*   idx2   = (int*)(ws + 131072);        // 128 KB
    float* gap    = (float*)(ws + 262144);      // 128 KB
    int*   cnt    = (int*)(ws + 393216);        // 128 KB
    int*   off    = (int*)(ws + 524288);        // 128 KB
    u16*   Wfrag  = (u16*)(ws + 655360);        // 512 KB fragment-major

    hipLaunchKernelGGL(k_wconv, dim3(64), dim3(256), 0, stream, W, Wfrag);
    hipLaunchKernelGGL(k_logits, dim3(1024), dim3(256), 0, stream,
                       A, Wfrag, b, logits, probsmax, choice, idx2, gap);
    hipLaunchKernelGGL(k_refine, dim3(128), dim3(256), 0, stream,
                       A, W, b, choice, idx2, gap);
    hipLaunchKernelGGL(k_count, dim3(128), dim3(256), 0, stream, choice, cnt);
    hipLaunchKernelGGL(k_scan, dim3(4), dim3(64), 0, stream, cnt, off);
    hipLaunchKernelGGL(k_emit, dim3(128), dim3(256), 0, stream, choice, off, expert_out);
}

// Round 6
// 185.734 us; speedup vs baseline: 3.8664x; 1.1020x over previous
//
#include <hip/hip_runtime.h>

#define HID 2048
#define NE 64
#define NTOK 32768        // GROUPS * TOKENS = 4 * 8192
#define CAP 160
#define GAP_THR 0.01f

typedef unsigned short u16;
typedef short bf16x8 __attribute__((ext_vector_type(8)));
typedef float f32x16 __attribute__((ext_vector_type(16)));

// fp32 -> bf16 hi (truncate) + bf16 lo (truncate of exact remainder).
static __device__ __forceinline__ void cvt8(const float4& a, const float4& b,
                                            bf16x8& hi, bf16x8& lo) {
    float f[8] = {a.x, a.y, a.z, a.w, b.x, b.y, b.z, b.w};
#pragma unroll
    for (int j = 0; j < 8; ++j) {
        const unsigned u = __float_as_uint(f[j]);
        const unsigned h = u >> 16;
        const float r = f[j] - __uint_as_float(h << 16);   // exact
        hi[j] = (short)h;
        lo[j] = (short)(__float_as_uint(r) >> 16);
    }
}

// ---------------------------------------------------------------------------
// K0: split W into bf16 hi/lo and store in MFMA fragment-major order.
// Step S = kq*32+ks owns 4 KB: chunks [h0|h1|l0|l1], each 1 KB = lane*8 u16.
// ---------------------------------------------------------------------------
__global__ void k_wconv(const float* __restrict__ W, u16* __restrict__ Wfrag)
{
    const int idx = blockIdx.x * 256 + threadIdx.x;   // 0..16383
    if (idx >= NE * (HID / 8)) return;
    const int e  = idx >> 8;          // expert 0..63
    const int k8 = idx & 255;         // 8-float chunk 0..255
    const int k0 = k8 * 8;
    const int kq   = k0 >> 9;
    const int kk   = k0 & 511;
    const int ks   = kk >> 4;
    const int khal = (kk >> 3) & 1;
    const int lane = (e & 31) + khal * 32;
    const int S    = kq * 32 + ks;

    bf16x8 hi, lo;
    const float4 a = *(const float4*)(W + (size_t)e * HID + k0);
    const float4 b = *(const float4*)(W + (size_t)e * HID + k0 + 4);
    cvt8(a, b, hi, lo);

    u16* base = Wfrag + (size_t)S * 2048 + (size_t)(e >> 5) * 512 + lane * 8;
    *(bf16x8*)(base)        = hi;     // chunk (e>>5)
    *(bf16x8*)(base + 1024) = lo;     // chunk 2+(e>>5)
}

// ---------------------------------------------------------------------------
// K1: logits via 3-term bf16-split MFMA. Block = 256 thr = 4 waves.
// A-stream (HBM-miss) prefetched 4 K-steps deep; W-stream (L2-hot) 2 deep.
// ---------------------------------------------------------------------------
__global__ __launch_bounds__(256, 4) void k_logits(
    const float* __restrict__ A, const u16* __restrict__ Wfrag,
    const float* __restrict__ bias,
    float* __restrict__ logits, float* __restrict__ probsmax,
    int* __restrict__ choice, int* __restrict__ idx2o, float* __restrict__ gapo)
{
    __shared__ float lds[4 * 32 * 65];    // [kq][token][65] (pad: conflict-free)
    const int tid  = threadIdx.x;
    const int lane = tid & 63;
    const int kq   = __builtin_amdgcn_readfirstlane(tid >> 6);  // 0..3 uniform
    const int tok0 = blockIdx.x * 32;
    const int trow = lane & 31;           // token (B-col) / expert (A-row)
    const int khal = lane >> 5;

    const float* abase = A + (size_t)(tok0 + trow) * HID + kq * 512 + khal * 8;
    const u16*   wbase = Wfrag + (size_t)(kq * 32) * 2048 + lane * 8;

    f32x16 acc0, acc1;
#pragma unroll
    for (int r = 0; r < 16; ++r) { acc0[r] = 0.0f; acc1[r] = 0.0f; }

    float4 p0a, p0b, p1a, p1b, p2a, p2b, p3a, p3b;   // 4-deep A prefetch
    bf16x8 w0h0, w0h1, w0l0, w0l1, w1h0, w1h1, w1l0, w1l1;

#define LOADA(P, KS) { P##a = *(const float4*)(abase + (KS) * 16);      \
                       P##b = *(const float4*)(abase + (KS) * 16 + 4); }
#define LOADW(G, KS) { const u16* wp = wbase + (size_t)(KS) * 2048;     \
                       G##h0 = *(const bf16x8*)(wp);                    \
                       G##h1 = *(const bf16x8*)(wp + 512);              \
                       G##l0 = *(const bf16x8*)(wp + 1024);             \
                       G##l1 = *(const bf16x8*)(wp + 1536); }
#define MFMA_ __builtin_amdgcn_mfma_f32_32x32x16_bf16
// consume A-slot P + W-slot G at step; optionally refill A (4 ahead), W (2 ahead)
#define STEP(P, G, RA, KA, RW, KW) {                                    \
    bf16x8 ah, al; cvt8(P##a, P##b, ah, al);                            \
    if (RA) LOADA(P, KA)                                                \
    acc0 = MFMA_(G##h0, ah, acc0, 0, 0, 0);                             \
    acc1 = MFMA_(G##h1, ah, acc1, 0, 0, 0);                             \
    acc0 = MFMA_(G##l0, ah, acc0, 0, 0, 0);                             \
    acc1 = MFMA_(G##l1, ah, acc1, 0, 0, 0);                             \
    acc0 = MFMA_(G##h0, al, acc0, 0, 0, 0);                             \
    acc1 = MFMA_(G##h1, al, acc1, 0, 0, 0);                             \
    if (RW) LOADW(G, KW)                                                \
}

    LOADA(p0, 0) LOADA(p1, 1) LOADA(p2, 2) LOADA(p3, 3)
    LOADW(w0, 0) LOADW(w1, 1)
#pragma unroll 1
    for (int ks = 0; ks < 24; ks += 4) {
        STEP(p0, w0, 1, ks + 4, 1, ks + 2)
        STEP(p1, w1, 1, ks + 5, 1, ks + 3)
        STEP(p2, w0, 1, ks + 6, 1, ks + 4)
        STEP(p3, w1, 1, ks + 7, 1, ks + 5)
    }
    STEP(p0, w0, 1, 28, 1, 26)
    STEP(p1, w1, 1, 29, 1, 27)
    STEP(p2, w0, 1, 30, 1, 28)
    STEP(p3, w1, 1, 31, 1, 29)
    STEP(p0, w0, 0, 0, 1, 30)
    STEP(p1, w1, 0, 0, 1, 31)
    STEP(p2, w0, 0, 0, 0, 0)
    STEP(p3, w1, 0, 0, 0, 0)
#undef STEP
#undef LOADA
#undef LOADW

    // C -> LDS: token = lane&31 (col), expert = (r&3)+8*(r>>2)+4*khal (row)
    {
        float* pl = lds + kq * 2080 + trow * 65;
#pragma unroll
        for (int r = 0; r < 16; ++r) {
            const int er = (r & 3) + 8 * (r >> 2) + 4 * khal;
            pl[er]      = acc0[r];
            pl[32 + er] = acc1[r];
        }
    }
    __syncthreads();

    // split-K reduce (+bias), coalesced logits store, stash row into plane 0
    {
        const int t  = tid >> 3;          // 0..31
        const int e0 = (tid & 7) * 8;
        float v[8];
#pragma unroll
        for (int i = 0; i < 8; ++i) {
            const int o = t * 65 + e0 + i;
            v[i] = lds[o] + lds[2080 + o] + lds[4160 + o] + lds[6240 + o]
                 + bias[e0 + i];
        }
        float* lp = logits + (size_t)(tok0 + t) * NE + e0;
        *(float4*)(lp)     = make_float4(v[0], v[1], v[2], v[3]);
        *(float4*)(lp + 4) = make_float4(v[4], v[5], v[6], v[7]);
#pragma unroll
        for (int i = 0; i < 8; ++i) lds[t * 65 + e0 + i] = v[i];
    }
    __syncthreads();

    // per-token epilogue: top-2 + softmax denominator
    if (tid < 32) {
        const int t = tid;
        float m1 = -3.4e38f, m2 = -3.4e38f;
        int i1 = 0, i2 = 0;
#pragma unroll
        for (int e = 0; e < NE; ++e) {
            const float vv = lds[t * 65 + e];
            if (vv > m1)      { m2 = m1; i2 = i1; m1 = vv; i1 = e; }
            else if (vv > m2) { m2 = vv; i2 = e; }
        }
        float s = 0.0f;
#pragma unroll
        for (int e = 0; e < NE; ++e)
            s += __expf(lds[t * 65 + e] - m1);
        const int g2 = tok0 + t;
        probsmax[g2] = 1.0f / s;          // max prob = exp(0)/sum
        choice[g2]   = i1;
        idx2o[g2]    = i2;
        gapo[g2]     = m1 - m2;
    }
}

// ---------------------------------------------------------------------------
// K1b: fp64 refinement of near-tie argmax, wave-cooperative.
// 1 wave per 64 tokens; flagged tokens processed one-at-a-time by all 64
// lanes (lane-split H, fp64, shuffle reduce).
// ---------------------------------------------------------------------------
__global__ __launch_bounds__(64) void k_refine(
    const float* __restrict__ A, const float* __restrict__ W,
    const float* __restrict__ bias,
    int* __restrict__ choice, const int* __restrict__ idx2,
    const float* __restrict__ gap)
{
    const int lane = threadIdx.x;
    const int gt0  = blockIdx.x * 64;
    const int gtl  = gt0 + lane;
    const bool flag = (gap[gtl] < GAP_THR) && (choice[gtl] != idx2[gtl]);
    unsigned long long m = __ballot(flag);
    while (m) {
        const int t = (int)__ffsll((long long)m) - 1;
        m &= m - 1;
        const int gt = gt0 + t;
        const int i1 = choice[gt], i2 = idx2[gt];
        const float* a  = A + (size_t)gt * HID;
        const float* w1 = W + (size_t)i1 * HID;
        const float* w2 = W + (size_t)i2 * HID;
        double d1 = 0.0, d2 = 0.0;
#pragma unroll 4
        for (int h = lane; h < HID; h += 64) {
            const double av = (double)a[h];
            d1 += av * (double)w1[h];
            d2 += av * (double)w2[h];
        }
#pragma unroll
        for (int o = 32; o; o >>= 1) {
            d1 += __shfl_xor(d1, o);
            d2 += __shfl_xor(d2, o);
        }
        if (lane == 0) {
            d1 += (double)bias[i1];
            d2 += (double)bias[i2];
            if (d2 > d1 || (d2 == d1 && i2 < i1)) choice[gt] = i2;
        }
    }
}

// ---------------------------------------------------------------------------
// K2: per-64-token-chunk histogram of expert choices (wave ballot).
// ---------------------------------------------------------------------------
__global__ void k_count(const int* __restrict__ choice, int* __restrict__ cnt)
{
    const int lane  = threadIdx.x & 63;
    const int wave  = threadIdx.x >> 6;
    const int chunk = blockIdx.x * 4 + wave;   // 0..511
    const int gt    = chunk * 64 + lane;
    const int c     = choice[gt];
    int mycnt = 0;
#pragma unroll 1
    for (int e = 0; e < NE; ++e) {
        const unsigned long long m = __ballot(c == e);
        if (lane == e) mycnt = (int)__popcll(m);
    }
    cnt[chunk * 64 + lane] = mycnt;
}

// ---------------------------------------------------------------------------
// K3: exclusive scan of 128 chunk-histograms per group, staged in LDS.
// Block g: coalesced load 128x64 ints -> LDS, 64 threads scan (bank = tid%32,
// conflict-free), coalesced store.
// ---------------------------------------------------------------------------
__global__ __launch_bounds__(256) void k_scan(const int* __restrict__ cnt,
                                              int* __restrict__ off)
{
    __shared__ int s[128 * 64];       // 32 KB
    const int tid  = threadIdx.x;
    const int base = blockIdx.x * 128 * 64;
#pragma unroll
    for (int i = 0; i < 32; ++i)
        s[tid + 256 * i] = cnt[base + tid + 256 * i];
    __syncthreads();
    if (tid < 64) {
        int run = 0;
#pragma unroll 1
        for (int c = 0; c < 128; ++c) {
            const int idx = c * 64 + tid;
            const int v = s[idx];
            s[idx] = run;
            run += v;
        }
    }
    __syncthreads();
#pragma unroll
    for (int i = 0; i < 32; ++i)
        off[base + tid + 256 * i] = s[tid + 256 * i];
}

// ---------------------------------------------------------------------------
// K4: emit expert_index rows (0/1 as fp32) with capacity mask.
// ---------------------------------------------------------------------------
__global__ void k_emit(const int* __restrict__ choice, const int* __restrict__ off,
                       float* __restrict__ eout)
{
    const int lane  = threadIdx.x & 63;
    const int wave  = threadIdx.x >> 6;
    const int chunk = blockIdx.x * 4 + wave;
    const int gt    = chunk * 64 + lane;
    const int c     = choice[gt];
    unsigned long long mymask = 0;
#pragma unroll 1
    for (int e = 0; e < NE; ++e) {
        const unsigned long long m = __ballot(c == e);
        if (c == e) mymask = m;
    }
    const int pre  = (int)__popcll(mymask & ((1ull << lane) - 1ull));
    const int base = off[chunk * 64 + c];
    const float val = (base + pre + 1 <= CAP) ? 1.0f : 0.0f;
    float* op = eout + (size_t)gt * NE;
#pragma unroll
    for (int i = 0; i < 16; ++i) {
        float4 v;
        v.x = (4*i+0 == c) ? val : 0.0f;
        v.y = (4*i+1 == c) ? val : 0.0f;
        v.z = (4*i+2 == c) ? val : 0.0f;
        v.w = (4*i+3 == c) ? val : 0.0f;
        ((float4*)op)[i] = v;
    }
}

// ---------------------------------------------------------------------------
extern "C" void kernel_launch(void* const* d_in, const int* in_sizes, int n_in,
                              void* d_out, int out_size, void* d_ws, size_t ws_size,
                              hipStream_t stream) {
    const float* A = (const float*)d_in[0];   // [4, 8192, 2048]
    const float* W = (const float*)d_in[1];   // [64, 2048]
    const float* b = (const float*)d_in[2];   // [64]

    float* out        = (float*)d_out;
    float* expert_out = out;                        // 2,097,152
    float* probsmax   = out + 2097152;              //    32,768
    float* logits     = out + 2097152 + 32768;      // 2,097,152

    char* ws      = (char*)d_ws;
    int*   choice = (int*)(ws);                 // 128 KB
    int*   idx2   = (int*)(ws + 131072);        // 128 KB
    float* gap    = (float*)(ws + 262144);      // 128 KB
    int*   cnt    = (int*)(ws + 393216);        // 128 KB
    int*   off    = (int*)(ws + 524288);        // 128 KB
    u16*   Wfrag  = (u16*)(ws + 655360);        // 512 KB fragment-major

    hipLaunchKernelGGL(k_wconv, dim3(64), dim3(256), 0, stream, W, Wfrag);
    hipLaunchKernelGGL(k_logits, dim3(1024), dim3(256), 0, stream,
                       A, Wfrag, b, logits, probsmax, choice, idx2, gap);
    hipLaunchKernelGGL(k_refine, dim3(512), dim3(64), 0, stream,
                       A, W, b, choice, idx2, gap);
    hipLaunchKernelGGL(k_count, dim3(128), dim3(256), 0, stream, choice, cnt);
    hipLaunchKernelGGL(k_scan, dim3(4), dim3(256), 0, stream, cnt, off);
    hipLaunchKernelGGL(k_emit, dim3(128), dim3(256), 0, stream, choice, off, expert_out);
}

// Round 7
// 114.889 us; speedup vs baseline: 6.2505x; 1.6166x over previous
//
#include <hip/hip_runtime.h>

#define HID 2048
#define NE 64
#define NTOK 32768        // GROUPS * TOKENS = 4 * 8192
#define CAP 160
#define GAP_THR 0.01f

typedef unsigned short u16;
typedef short bf16x8 __attribute__((ext_vector_type(8)));
typedef float f32x16 __attribute__((ext_vector_type(16)));

typedef __attribute__((address_space(1))) const void gvoid;
typedef __attribute__((address_space(3))) void lvoid;
#define GLOAD_LDS16(gp, lp) \
    __builtin_amdgcn_global_load_lds((gvoid*)(gp), (lvoid*)(lp), 16, 0, 0)

// fp32 -> bf16 hi (truncate) + bf16 lo (truncate of exact remainder).
static __device__ __forceinline__ void cvt8(const float4& a, const float4& b,
                                            bf16x8& hi, bf16x8& lo) {
    float f[8] = {a.x, a.y, a.z, a.w, b.x, b.y, b.z, b.w};
#pragma unroll
    for (int j = 0; j < 8; ++j) {
        const unsigned u = __float_as_uint(f[j]);
        const unsigned h = u >> 16;
        const float r = f[j] - __uint_as_float(h << 16);   // exact
        hi[j] = (short)h;
        lo[j] = (short)(__float_as_uint(r) >> 16);
    }
}

// ---------------------------------------------------------------------------
// K0: split W into bf16 hi/lo, fragment-major: step S owns 4KB [h0|h1|l0|l1],
// each chunk 1KB = lane*16B.  S = global K-step = k0/16.
// ---------------------------------------------------------------------------
__global__ void k_wconv(const float* __restrict__ W, u16* __restrict__ Wfrag)
{
    const int idx = blockIdx.x * 256 + threadIdx.x;   // 0..16383
    if (idx >= NE * (HID / 8)) return;
    const int e  = idx >> 8;          // expert 0..63
    const int k0 = (idx & 255) * 8;
    const int S    = k0 >> 4;
    const int khal = (k0 >> 3) & 1;
    const int lane = (e & 31) + khal * 32;

    bf16x8 hi, lo;
    const float4 a = *(const float4*)(W + (size_t)e * HID + k0);
    const float4 b = *(const float4*)(W + (size_t)e * HID + k0 + 4);
    cvt8(a, b, hi, lo);

    u16* base = Wfrag + (size_t)S * 2048 + (size_t)(e >> 5) * 512 + lane * 8;
    *(bf16x8*)(base)        = hi;     // chunk (e>>5)
    *(bf16x8*)(base + 1024) = lo;     // chunk 2+(e>>5)
}

// ---------------------------------------------------------------------------
// K1: logits via 3-term bf16-split MFMA, LDS-staged A.
// Block = 256 thr = 4 waves, 32 tokens.  A staged in [32 rows][128 floats]
// chunks (16 KB) via global_load_lds, double-buffered, XOR-swizzled on the
// GLOBAL source (LDS dest linear): LDS slot [row][g] holds global granule
// g^row -> compute b128 reads spread 8 bank-groups.  Wave kq computes
// K-steps {c*8+kq*2, +1} per chunk; split-K reduce in epilogue.
// W read from fragment-major Wfrag (coalesced 1KB streams, L2-hot),
// issued at end of chunk body so the barrier's vmcnt-drain completes them.
// ---------------------------------------------------------------------------
__global__ __launch_bounds__(256, 4) void k_logits(
    const float* __restrict__ A, const u16* __restrict__ Wfrag,
    const float* __restrict__ bias,
    float* __restrict__ logits, float* __restrict__ probsmax,
    int* __restrict__ choice, int* __restrict__ idx2o, float* __restrict__ gapo)
{
    __shared__ float smem[8448];          // [0,8192): A dbuf; reused as lacc
    const int tid  = threadIdx.x;
    const int lane = tid & 63;
    const int kq   = __builtin_amdgcn_readfirstlane(tid >> 6);  // 0..3 uniform
    const int tok0 = blockIdx.x * 32;
    const int trow = lane & 31;           // token row (B-col)
    const int khal = lane >> 5;

    // ---- DMA source pointers: wave kq stages rows [kq*8, kq*8+8) ----
    // instr i covers rows kq*8+i*2+(lane>>5); lane slot sg=lane&31 holds
    // global granule sg^row (inverse swizzle on source, LDS stays linear).
    const int sg = lane & 31;
    const int r0 = kq * 8 + khal;
#define GPTR(i) (A + (size_t)(tok0 + r0 + 2*(i)) * HID + ((sg ^ (r0 + 2*(i))) << 2))
    const float* gp0 = GPTR(0);
    const float* gp1 = GPTR(1);
    const float* gp2 = GPTR(2);
    const float* gp3 = GPTR(3);
#undef GPTR

    // ---- W fragment pointer (per-lane 16B, coalesced 1KB/instr) ----
    const u16* wbase = Wfrag + lane * 8;

    f32x16 acc0, acc1;
#pragma unroll
    for (int r = 0; r < 16; ++r) { acc0[r] = 0.0f; acc1[r] = 0.0f; }

    bf16x8 wh0[2], wh1[2], wl0[2], wl1[2];    // W frags for the 2 steps of a chunk
#define MFMA_ __builtin_amdgcn_mfma_f32_32x32x16_bf16
#define LOADW(C) {                                                        \
    _Pragma("unroll")                                                     \
    for (int s = 0; s < 2; ++s) {                                         \
        const u16* wp = wbase + (size_t)((C) * 8 + kq * 2 + s) * 2048;    \
        wh0[s] = *(const bf16x8*)(wp);                                    \
        wh1[s] = *(const bf16x8*)(wp + 512);                              \
        wl0[s] = *(const bf16x8*)(wp + 1024);                             \
        wl1[s] = *(const bf16x8*)(wp + 1536);                             \
    } }
#define DMA(BUF) {                                                        \
    float* dst = smem + (BUF) * 4096 + kq * 1024;                         \
    GLOAD_LDS16(gp0, dst);                                                \
    GLOAD_LDS16(gp1, dst + 256);                                          \
    GLOAD_LDS16(gp2, dst + 512);                                          \
    GLOAD_LDS16(gp3, dst + 768);                                          \
    gp0 += 128; gp1 += 128; gp2 += 128; gp3 += 128; }

    // prologue: stage chunk 0, load W for chunk 0
    DMA(0)
    LOADW(0)
    __syncthreads();                      // vmcnt(0) drain + barrier

    int buf = 0;
#pragma unroll 1
    for (int c = 0; c < 16; ++c) {
        if (c < 15) DMA(buf ^ 1)          // prefetch next chunk into other buf
        const float* base2 = smem + buf * 4096 + trow * 128;
#pragma unroll
        for (int s = 0; s < 2; ++s) {
            const int g0 = (kq * 2 + s) * 4 + khal * 2;
            const float4 va = *(const float4*)(base2 + ((g0 ^ trow) << 2));
            const float4 vb = *(const float4*)(base2 + (((g0 + 1) ^ trow) << 2));
            bf16x8 ah, al; cvt8(va, vb, ah, al);
            acc0 = MFMA_(wh0[s], ah, acc0, 0, 0, 0);
            acc1 = MFMA_(wh1[s], ah, acc1, 0, 0, 0);
            acc0 = MFMA_(wl0[s], ah, acc0, 0, 0, 0);
            acc1 = MFMA_(wl1[s], ah, acc1, 0, 0, 0);
            acc0 = MFMA_(wh0[s], al, acc0, 0, 0, 0);
            acc1 = MFMA_(wh1[s], al, acc1, 0, 0, 0);
        }
        if (c < 15) LOADW(c + 1)          // in flight through the barrier drain
        __syncthreads();                  // DMA+W complete; buf roles swap
        buf ^= 1;
    }
#undef DMA
#undef LOADW

    // ---- epilogue: smem reused as lacc[4][32][65] ----
    float (*lacc)[65] = (float(*)[65])smem;
    {
        float* pl = smem + kq * 2080 + trow * 65;
#pragma unroll
        for (int r = 0; r < 16; ++r) {
            const int er = (r & 3) + 8 * (r >> 2) + 4 * khal;
            pl[er]      = acc0[r];
            pl[32 + er] = acc1[r];
        }
    }
    __syncthreads();

    // split-K reduce (+bias), coalesced logits store, stash row into plane 0
    {
        const int t  = tid >> 3;          // 0..31
        const int e0 = (tid & 7) * 8;
        float v[8];
#pragma unroll
        for (int i = 0; i < 8; ++i) {
            const int o = t * 65 + e0 + i;
            v[i] = smem[o] + smem[2080 + o] + smem[4160 + o] + smem[6240 + o]
                 + bias[e0 + i];
        }
        float* lp = logits + (size_t)(tok0 + t) * NE + e0;
        *(float4*)(lp)     = make_float4(v[0], v[1], v[2], v[3]);
        *(float4*)(lp + 4) = make_float4(v[4], v[5], v[6], v[7]);
#pragma unroll
        for (int i = 0; i < 8; ++i) smem[t * 65 + e0 + i] = v[i];
    }
    __syncthreads();

    // per-token epilogue: top-2 + softmax denominator
    if (tid < 32) {
        const int t = tid;
        float m1 = -3.4e38f, m2 = -3.4e38f;
        int i1 = 0, i2 = 0;
#pragma unroll
        for (int e = 0; e < NE; ++e) {
            const float vv = lacc[0][t * 65 + e - t * 65 + e * 0] ;  // placeholder avoided
            (void)vv;
            break;
        }
        // (clean scan below — single pass over the stashed row)
        m1 = -3.4e38f; m2 = -3.4e38f; i1 = 0; i2 = 0;
#pragma unroll
        for (int e = 0; e < NE; ++e) {
            const float vv = smem[t * 65 + e];
            if (vv > m1)      { m2 = m1; i2 = i1; m1 = vv; i1 = e; }
            else if (vv > m2) { m2 = vv; i2 = e; }
        }
        float sden = 0.0f;
#pragma unroll
        for (int e = 0; e < NE; ++e)
            sden += __expf(smem[t * 65 + e] - m1);
        const int g2 = tok0 + t;
        probsmax[g2] = 1.0f / sden;       // max prob = exp(0)/sum
        choice[g2]   = i1;
        idx2o[g2]    = i2;
        gapo[g2]     = m1 - m2;
    }
}

// ---------------------------------------------------------------------------
// K1b: fp64 refinement of near-tie argmax, wave-cooperative.
// ---------------------------------------------------------------------------
__global__ __launch_bounds__(64) void k_refine(
    const float* __restrict__ A, const float* __restrict__ W,
    const float* __restrict__ bias,
    int* __restrict__ choice, const int* __restrict__ idx2,
    const float* __restrict__ gap)
{
    const int lane = threadIdx.x;
    const int gt0  = blockIdx.x * 64;
    const int gtl  = gt0 + lane;
    const bool flag = (gap[gtl] < GAP_THR) && (choice[gtl] != idx2[gtl]);
    unsigned long long m = __ballot(flag);
    while (m) {
        const int t = (int)__ffsll((long long)m) - 1;
        m &= m - 1;
        const int gt = gt0 + t;
        const int i1 = choice[gt], i2 = idx2[gt];
        const float* a  = A + (size_t)gt * HID;
        const float* w1 = W + (size_t)i1 * HID;
        const float* w2 = W + (size_t)i2 * HID;
        double d1 = 0.0, d2 = 0.0;
#pragma unroll 4
        for (int h = lane; h < HID; h += 64) {
            const double av = (double)a[h];
            d1 += av * (double)w1[h];
            d2 += av * (double)w2[h];
        }
#pragma unroll
        for (int o = 32; o; o >>= 1) {
            d1 += __shfl_xor(d1, o);
            d2 += __shfl_xor(d2, o);
        }
        if (lane == 0) {
            d1 += (double)bias[i1];
            d2 += (double)bias[i2];
            if (d2 > d1 || (d2 == d1 && i2 < i1)) choice[gt] = i2;
        }
    }
}

// ---------------------------------------------------------------------------
// K2: per-64-token-chunk histogram of expert choices (wave ballot).
// ---------------------------------------------------------------------------
__global__ void k_count(const int* __restrict__ choice, int* __restrict__ cnt)
{
    const int lane  = threadIdx.x & 63;
    const int wave  = threadIdx.x >> 6;
    const int chunk = blockIdx.x * 4 + wave;   // 0..511
    const int gt    = chunk * 64 + lane;
    const int c     = choice[gt];
    int mycnt = 0;
#pragma unroll 1
    for (int e = 0; e < NE; ++e) {
        const unsigned long long m = __ballot(c == e);
        if (lane == e) mycnt = (int)__popcll(m);
    }
    cnt[chunk * 64 + lane] = mycnt;
}

// ---------------------------------------------------------------------------
// K3: exclusive scan of 128 chunk-histograms per group, staged in LDS.
// ---------------------------------------------------------------------------
__global__ __launch_bounds__(256) void k_scan(const int* __restrict__ cnt,
                                              int* __restrict__ off)
{
    __shared__ int s[128 * 64];       // 32 KB
    const int tid  = threadIdx.x;
    const int base = blockIdx.x * 128 * 64;
#pragma unroll
    for (int i = 0; i < 32; ++i)
        s[tid + 256 * i] = cnt[base + tid + 256 * i];
    __syncthreads();
    if (tid < 64) {
        int run = 0;
#pragma unroll 1
        for (int c = 0; c < 128; ++c) {
            const int idx = c * 64 + tid;
            const int v = s[idx];
            s[idx] = run;
            run += v;
        }
    }
    __syncthreads();
#pragma unroll
    for (int i = 0; i < 32; ++i)
        off[base + tid + 256 * i] = s[tid + 256 * i];
}

// ---------------------------------------------------------------------------
// K4: emit expert_index rows (0/1 as fp32) with capacity mask.
// ---------------------------------------------------------------------------
__global__ void k_emit(const int* __restrict__ choice, const int* __restrict__ off,
                       float* __restrict__ eout)
{
    const int lane  = threadIdx.x & 63;
    const int wave  = threadIdx.x >> 6;
    const int chunk = blockIdx.x * 4 + wave;
    const int gt    = chunk * 64 + lane;
    const int c     = choice[gt];
    unsigned long long mymask = 0;
#pragma unroll 1
    for (int e = 0; e < NE; ++e) {
        const unsigned long long m = __ballot(c == e);
        if (c == e) mymask = m;
    }
    const int pre  = (int)__popcll(mymask & ((1ull << lane) - 1ull));
    const int base = off[chunk * 64 + c];
    const float val = (base + pre + 1 <= CAP) ? 1.0f : 0.0f;
    float* op = eout + (size_t)gt * NE;
#pragma unroll
    for (int i = 0; i < 16; ++i) {
        float4 v;
        v.x = (4*i+0 == c) ? val : 0.0f;
        v.y = (4*i+1 == c) ? val : 0.0f;
        v.z = (4*i+2 == c) ? val : 0.0f;
        v.w = (4*i+3 == c) ? val : 0.0f;
        ((float4*)op)[i] = v;
    }
}

// ---------------------------------------------------------------------------
extern "C" void kernel_launch(void* const* d_in, const int* in_sizes, int n_in,
                              void* d_out, int out_size, void* d_ws, size_t ws_size,
                              hipStream_t stream) {
    const float* A = (const float*)d_in[0];   // [4, 8192, 2048]
    const float* W = (const float*)d_in[1];   // [64, 2048]
    const float* b = (const float*)d_in[2];   // [64]

    float* out        = (float*)d_out;
    float* expert_out = out;                        // 2,097,152
    float* probsmax   = out + 2097152;              //    32,768
    float* logits     = out + 2097152 + 32768;      // 2,097,152

    char* ws      = (char*)d_ws;
    int*   choice = (int*)(ws);                 // 128 KB
    int*   idx2   = (int*)(ws + 131072);        // 128 KB
    float* gap    = (float*)(ws + 262144);      // 128 KB
    int*   cnt    = (int*)(ws + 393216);        // 128 KB
    int*   off    = (int*)(ws + 524288);        // 128 KB
    u16*   Wfrag  = (u16*)(ws + 655360);        // 512 KB fragment-major

    hipLaunchKernelGGL(k_wconv, dim3(64), dim3(256), 0, stream, W, Wfrag);
    hipLaunchKernelGGL(k_logits, dim3(1024), dim3(256), 0, stream,
                       A, Wfrag, b, logits, probsmax, choice, idx2, gap);
    hipLaunchKernelGGL(k_refine, dim3(512), dim3(64), 0, stream,
                       A, W, b, choice, idx2, gap);
    hipLaunchKernelGGL(k_count, dim3(128), dim3(256), 0, stream, choice, cnt);
    hipLaunchKernelGGL(k_scan, dim3(4), dim3(256), 0, stream, cnt, off);
    hipLaunchKernelGGL(k_emit, dim3(128), dim3(256), 0, stream, choice, off, expert_out);
}